// Round 9
// baseline (356.388 us; speedup 1.0000x reference)
//
#include <hip/hip_runtime.h>
#include <stdint.h>

// z: [16,1024,256] fp32 -> N=16384 rows, D=256
// embedding: [8192,256] fp32 -> K=8192 codes
// out = [ z_q (4194304 f32) | loss (1 f32) | indices (16384 as f32) ]
#define N_ROWS   16384
#define DIM      256
#define N_CODES  8192
#define ZQ_ELEMS 4194304

typedef _Float16 f16x8 __attribute__((ext_vector_type(8)));
typedef _Float16 f16x4 __attribute__((ext_vector_type(4)));
typedef float    f32x16 __attribute__((ext_vector_type(16)));
typedef unsigned long long u64;

// ---- workspace (bytes): et 8.52 MB | pkeys 128 KB | cnt 512 B ----
// et layout in f16x8 units (16 B) — CONTIGUOUS PER SPLIT (L2-set-uniform):
//   hi plane: sp*65536 + ksg*4096 + cw*2 + h   (sp=code>>11, cw=code&2047)
//   lo plane: +262144
//   aug:      524288 + code  ({||e||^2_hi, ||e||^2_lo, 0...})
// pkeys: ONE u64 per row, merged across the 4 code-splits by atomicMin.
// cnt:   one u32 per 128-row panel (128); 4th finisher runs the fused final.
// R9: vq_final FUSED into vq_main WITHOUT any __threadfence (R6 lesson: the
// fence = per-XCD L2 writeback+invalidate -> evicts the A panels, MfmaUtil
// 58->21%). Protocol is atomics end-to-end: atomicMin's are committed at the
// device coherence point (s_waitcnt vmcnt(0) after issue), THEN the panel
// counter is bumped; the 4th finisher re-reads pkeys via no-op atomicMin
// (coherence-point read, never stale L1/L2). Cross-block accounting showed
// the separate vq_final launch cost ~70 us (non-main time: 97 us @3 launches
// vs 28 us @2 launches in R6) — bigger than any remaining in-loop stall.
#define WS_ET  0
#define WS_PK  (8519680)
#define WS_CNT (8650752)

static __device__ __forceinline__ u64 packkey(float d, int c) {
    unsigned int u = __float_as_uint(d);
    u ^= ((unsigned int)((int)u >> 31)) | 0x80000000u;   // monotone float map
    return ((u64)u << 32) | (unsigned int)c;             // min => (dist, then idx)
}

// ---------------- prep: e-only, 256 fat blocks x 32 codes; init pk/cnt ----------------
__global__ void vq_prep(const float* __restrict__ emb, _Float16* __restrict__ et,
                        u64* __restrict__ pkeys, unsigned int* __restrict__ cnt,
                        float* __restrict__ loss_ptr) {
    __shared__ _Float16 sh[2][32][272];          // 34,816 B (272-stride: conflict-free)
    const int t = threadIdx.x, w = t >> 6, l = t & 63;
    if (blockIdx.x == 0 && t == 0) *loss_ptr = 0.0f;
    if (t == 0 && blockIdx.x < 128) cnt[blockIdx.x] = 0;
    if (t < 64) pkeys[blockIdx.x * 64 + t] = ~0ULL;
    const int code0 = blockIdx.x * 32;
    const int sp0 = code0 >> 11, cw0 = code0 & 2047;   // block never straddles a split
    #pragma unroll
    for (int j = 0; j < 8; ++j) {
        const int cl = w * 8 + j;
        float4 v = *(const float4*)(emb + (size_t)(code0 + cl) * DIM + l * 4);
        float xs[4] = {v.x, v.y, v.z, v.w};
        f16x4 hh, lo;
        float s = 0.0f;
        #pragma unroll
        for (int i = 0; i < 4; ++i) {
            _Float16 h = (_Float16)xs[i];
            hh[i] = h;
            lo[i] = (_Float16)(xs[i] - (float)h);
            s += xs[i] * xs[i];
        }
        *(f16x4*)&sh[0][cl][l * 4] = hh;
        *(f16x4*)&sh[1][cl][l * 4] = lo;
        #pragma unroll
        for (int off = 32; off > 0; off >>= 1) s += __shfl_down(s, off, 64);
        if (l == 0) {                            // aug: {norm_hi, norm_lo, 0..}
            _Float16 nh = (_Float16)s;
            _Float16 nl = (_Float16)(s - (float)nh);
            f16x8 aug;
            #pragma unroll
            for (int i = 0; i < 8; ++i) aug[i] = (_Float16)0;
            aug[0] = nh; aug[1] = nl;
            *(f16x8*)(et + ((size_t)524288 + code0 + cl) * 8) = aug;
        }
    }
    __syncthreads();
    #pragma unroll
    for (int pp = 0; pp < 8; ++pp) {             // 2048 units, 1-KB coalesced stores
        const int gi = pp * 256 + t;
        const int p = gi >> 10, ks = (gi >> 6) & 15, cl = (gi >> 1) & 31, h = gi & 1;
        f16x8 frag = *(const f16x8*)&sh[p][cl][ks * 16 + h * 8];
        const size_t unit = (size_t)p * 262144 + (size_t)sp0 * 65536
                          + (size_t)ks * 4096 + (size_t)(cw0 + cl) * 2 + h;
        *(f16x8*)(et + unit * 8) = frag;
    }
}

// ---------------- main: 128-row blocks, 4-way XCD-pinned split, fused final ----------------
// grid 512 = 128 row-blocks x 4 code-splits; sp = blockIdx&3 (round-robin %8 -> XCD
// gives each XCD one split; its CONTIGUOUS 2.1-MB panel is L2-resident).
// 512 threads (8 waves, 2/SIMD, 1 blk/CU). A = e from global with explicit
// one-ksg-ahead double-buffer prefetch + next-ci ksg0 prefetch before fold.
// B = z (-2z hi/lo f16) staged in-kernel, LDS row stride 1040 B (conflict-free).
// Aug-MFMA-first with C=0 initializes acc AND adds ||e||^2.
// Epilogue (4th finisher per panel): z_q/idx/loss gather; z reconstructed from
// this block's own LDS (z = -(hi+lo)/2, exact) — z is never re-read from HBM.
// LDS: z 133,120 + run/bestc 8,192 = 141,312 B.
__global__ __launch_bounds__(512, 2)
void vq_main(const float* __restrict__ z, const float* __restrict__ emb,
             const _Float16* __restrict__ et, u64* __restrict__ pkeys,
             unsigned int* __restrict__ cnt,
             float* __restrict__ zq_out, float* __restrict__ loss_out,
             float* __restrict__ idx_out) {
    extern __shared__ char smem[];
    u64* run = (u64*)(smem + 133120);            // [8][128]
    int* bestc = (int*)(smem + 133120);          // reused after the merge

    const int tid = threadIdx.x;
    const int w = tid >> 6, L = tid & 63, lo5 = L & 31, hi1 = L >> 5;
    const int rb = blockIdx.x >> 2, sp = blockIdx.x & 3;
    const int row0 = rb * 128, codeS = sp * 2048;

    // ---- stage z: coalesced f32 loads -> (-2z) hi/lo -> lane-linear ds_write ----
    const float* zr = z + (size_t)row0 * DIM;
    #pragma unroll
    for (int jj = 0; jj < 16; ++jj) {
        const int idx = jj * 512 + tid;          // float4 index in [0,8192)
        const int r = idx >> 6, q = idx & 63;    // row, dim-quad
        float4 v = *(const float4*)(zr + (size_t)r * DIM + q * 4);
        float xs[4] = {v.x, v.y, v.z, v.w};
        f16x4 hh, lo;
        #pragma unroll
        for (int i = 0; i < 4; ++i) {
            const float m2 = -2.0f * xs[i];      // planes carry -2z
            _Float16 h = (_Float16)m2;
            hh[i] = h;
            lo[i] = (_Float16)(m2 - (float)h);
        }
        char* base = smem + r * 1040 + q * 8;
        *(f16x4*)(base) = hh;                    // hi plane
        *(f16x4*)(base + 512) = lo;              // lo plane
    }
    run[tid] = ~0ULL;
    run[tid + 512] = ~0ULL;

    f16x8 bz;                                    // aug B: B[k0]=B[k1]=1 (hi1=0), else 0
    #pragma unroll
    for (int i = 0; i < 8; ++i) bz[i] = (_Float16)0;
    if (hi1 == 0) { bz[0] = (_Float16)1; bz[1] = (_Float16)1; }

    f32x16 zacc;                                 // constant C=0 for aug MFMAs
    #pragma unroll
    for (int e = 0; e < 16; ++e) zacc[e] = 0.0f;

    const f16x8* eb  = (const f16x8*)et;
    const f16x8* ebL = eb + 262144;              // lo plane
    const int laneU = lo5 * 2 + hi1;             // loop-invariant A voffset (units)
    const size_t spB = (size_t)sp * 65536;
    const char* zbA = smem + (lo5 * 1040 + hi1 * 16);
    const char* zbB = zbA + 66560;               // rows 64..127 (imm stays < 64 KB)

    // prefetch aug-A for ci=0 (hi1=1 lanes get other norms: finite, x0 in MFMA)
    f16x8 paug[2];
    {
        const int c0 = codeS + w * 64;
        paug[0] = eb[(size_t)524288 + c0 + lo5];
        paug[1] = eb[(size_t)524288 + c0 + 32 + lo5];
    }
    // prefetch A ksg=0 of ci=0 (overlaps staging + barrier)
    f16x8 aC0, aC1, aC2, aC3;
    {
        const size_t cu = spB + (size_t)(w * 64) * 2 + laneU;
        aC0 = eb[cu]; aC1 = eb[cu + 64]; aC2 = ebL[cu]; aC3 = ebL[cu + 64];
    }
    __syncthreads();

    for (int ci = 0; ci < 4; ++ci) {
        const int c0 = codeS + ci * 512 + w * 64;
        const size_t cu = spB + (size_t)(ci * 512 + w * 64) * 2 + laneU;
        f32x16 acc[2][4];

        // aug-first: acc = ||e||^2 broadcast (also the zero-init)
        __builtin_amdgcn_s_setprio(1);
        #pragma unroll
        for (int mt = 0; mt < 2; ++mt)
            #pragma unroll
            for (int nt = 0; nt < 4; ++nt)
                acc[mt][nt] = __builtin_amdgcn_mfma_f32_32x32x16_f16(paug[mt], bz, zacc, 0, 0, 0);
        __builtin_amdgcn_s_setprio(0);

        if (ci < 3) {                            // prefetch aug-A for ci+1
            const int c1 = codeS + (ci + 1) * 512 + w * 64;
            paug[0] = eb[(size_t)524288 + c1 + lo5];
            paug[1] = eb[(size_t)524288 + c1 + 32 + lo5];
        }

        #pragma unroll 4
        for (int ksg = 0; ksg < 16; ++ksg) {
            // A prefetch for ksg+1 (ksg=15 -> phantom, in-bounds, unused)
            const size_t ubn = cu + (size_t)(ksg + 1) * 4096;
            f16x8 aN0 = eb[ubn], aN1 = eb[ubn + 64];
            f16x8 aN2 = ebL[ubn], aN3 = ebL[ubn + 64];

            // first nt-half
            {
                f16x8 bh0 = *(const f16x8*)(zbA + (ksg * 32));
                f16x8 bl0 = *(const f16x8*)(zbA + (ksg * 32 + 512));
                f16x8 bh1 = *(const f16x8*)(zbA + (ksg * 32 + 33280));
                f16x8 bl1 = *(const f16x8*)(zbA + (ksg * 32 + 33280 + 512));
                __builtin_amdgcn_s_setprio(1);
                acc[0][0] = __builtin_amdgcn_mfma_f32_32x32x16_f16(aC0, bh0, acc[0][0], 0, 0, 0);
                acc[0][0] = __builtin_amdgcn_mfma_f32_32x32x16_f16(aC0, bl0, acc[0][0], 0, 0, 0);
                acc[0][0] = __builtin_amdgcn_mfma_f32_32x32x16_f16(aC2, bh0, acc[0][0], 0, 0, 0);
                acc[0][1] = __builtin_amdgcn_mfma_f32_32x32x16_f16(aC0, bh1, acc[0][1], 0, 0, 0);
                acc[0][1] = __builtin_amdgcn_mfma_f32_32x32x16_f16(aC0, bl1, acc[0][1], 0, 0, 0);
                acc[0][1] = __builtin_amdgcn_mfma_f32_32x32x16_f16(aC2, bh1, acc[0][1], 0, 0, 0);
                acc[1][0] = __builtin_amdgcn_mfma_f32_32x32x16_f16(aC1, bh0, acc[1][0], 0, 0, 0);
                acc[1][0] = __builtin_amdgcn_mfma_f32_32x32x16_f16(aC1, bl0, acc[1][0], 0, 0, 0);
                acc[1][0] = __builtin_amdgcn_mfma_f32_32x32x16_f16(aC3, bh0, acc[1][0], 0, 0, 0);
                acc[1][1] = __builtin_amdgcn_mfma_f32_32x32x16_f16(aC1, bh1, acc[1][1], 0, 0, 0);
                acc[1][1] = __builtin_amdgcn_mfma_f32_32x32x16_f16(aC1, bl1, acc[1][1], 0, 0, 0);
                acc[1][1] = __builtin_amdgcn_mfma_f32_32x32x16_f16(aC3, bh1, acc[1][1], 0, 0, 0);
                __builtin_amdgcn_s_setprio(0);
            }
            // second nt-half
            {
                f16x8 bh2 = *(const f16x8*)(zbB + (ksg * 32));
                f16x8 bl2 = *(const f16x8*)(zbB + (ksg * 32 + 512));
                f16x8 bh3 = *(const f16x8*)(zbB + (ksg * 32 + 33280));
                f16x8 bl3 = *(const f16x8*)(zbB + (ksg * 32 + 33280 + 512));
                __builtin_amdgcn_s_setprio(1);
                acc[0][2] = __builtin_amdgcn_mfma_f32_32x32x16_f16(aC0, bh2, acc[0][2], 0, 0, 0);
                acc[0][2] = __builtin_amdgcn_mfma_f32_32x32x16_f16(aC0, bl2, acc[0][2], 0, 0, 0);
                acc[0][2] = __builtin_amdgcn_mfma_f32_32x32x16_f16(aC2, bh2, acc[0][2], 0, 0, 0);
                acc[0][3] = __builtin_amdgcn_mfma_f32_32x32x16_f16(aC0, bh3, acc[0][3], 0, 0, 0);
                acc[0][3] = __builtin_amdgcn_mfma_f32_32x32x16_f16(aC0, bl3, acc[0][3], 0, 0, 0);
                acc[0][3] = __builtin_amdgcn_mfma_f32_32x32x16_f16(aC2, bh3, acc[0][3], 0, 0, 0);
                acc[1][2] = __builtin_amdgcn_mfma_f32_32x32x16_f16(aC1, bh2, acc[1][2], 0, 0, 0);
                acc[1][2] = __builtin_amdgcn_mfma_f32_32x32x16_f16(aC1, bl2, acc[1][2], 0, 0, 0);
                acc[1][2] = __builtin_amdgcn_mfma_f32_32x32x16_f16(aC3, bh2, acc[1][2], 0, 0, 0);
                acc[1][3] = __builtin_amdgcn_mfma_f32_32x32x16_f16(aC1, bh3, acc[1][3], 0, 0, 0);
                acc[1][3] = __builtin_amdgcn_mfma_f32_32x32x16_f16(aC1, bl3, acc[1][3], 0, 0, 0);
                acc[1][3] = __builtin_amdgcn_mfma_f32_32x32x16_f16(aC3, bh3, acc[1][3], 0, 0, 0);
                __builtin_amdgcn_s_setprio(0);
            }
            aC0 = aN0; aC1 = aN1; aC2 = aN2; aC3 = aN3;
        }

        // prefetch A ksg=0 of next ci BEFORE the fold (hides L2 latency under fold)
        {
            const size_t cuN = spB + (size_t)((((ci + 1) & 3) * 512) + w * 64) * 2 + laneU;
            aC0 = eb[cuN]; aC1 = eb[cuN + 64]; aC2 = ebL[cuN]; aC3 = ebL[cuN + 64];
        }

        // ---- fold: f32 min-tree + first-match index, one packkey per nt ----
        #pragma unroll
        for (int nt = 0; nt < 4; ++nt) {
            float mm[16];
            #pragma unroll
            for (int r = 0; r < 16; ++r)
                mm[r] = fminf(acc[0][nt][r], acc[1][nt][r]);
            #pragma unroll
            for (int s2 = 8; s2 > 0; s2 >>= 1)
                #pragma unroll
                for (int r = 0; r < 8; ++r)
                    if (r < s2) mm[r] = fminf(mm[r], mm[r + s2]);
            const float m = mm[0];
            int rel = 64;                        // sentinel; rc max 59
            #pragma unroll
            for (int mt = 0; mt < 2; ++mt)
                #pragma unroll
                for (int r = 0; r < 16; ++r) {
                    const int rc = mt * 32 + (r & 3) + 8 * (r >> 2);
                    const int cand = (acc[mt][nt][r] == m) ? rc : 64;
                    rel = cand < rel ? cand : rel;   // monotone rc => lowest code wins
                }
            u64 best = packkey(m, c0 + 4 * hi1 + rel);
            const u64 o = __shfl_xor(best, 32, 64);  // merge code-halves (same row)
            if (o < best) best = o;
            if (hi1 == 0) {
                u64* p = &run[w * 128 + nt * 32 + lo5];  // sole writer per slot
                if (best < *p) *p = best;
            }
        }
    }

    __syncthreads();
    if (tid < 128) {                             // merge 8 waves, then cross-split
        u64 k = run[tid];
        #pragma unroll
        for (int w2 = 1; w2 < 8; ++w2) { u64 o = run[w2 * 128 + tid]; if (o < k) k = o; }
        atomicMin(&pkeys[row0 + tid], k);
    }
    // commit our atomicMins at the device coherence point (NO cache-flushing
    // threadfence — that was R6's 2.4x regression) before announcing done.
    asm volatile("s_waitcnt vmcnt(0)" ::: "memory");
    __syncthreads();

    __shared__ unsigned int lastold;
    if (tid == 0) lastold = atomicAdd(&cnt[rb], 1u);
    __syncthreads();
    if (lastold == 3u) {                         // 4th finisher: fused final
        if (tid < 128) {
            // coherence-point read of merged key (no-op RMW, never-stale)
            const u64 k = atomicMin(&pkeys[row0 + tid], ~0ULL);
            const int code = (int)(k & 0xFFFFFFFFu);
            bestc[tid] = code;
            idx_out[row0 + tid] = (float)code;
        }
        __syncthreads();
        float lsum = 0.0f;
        #pragma unroll
        for (int rr = 0; rr < 16; ++rr) {
            const int rl = w * 16 + rr;          // 8 waves x 16 rows = 128
            const int rg = row0 + rl;
            const int code = bestc[rl];
            float4 ev = *(const float4*)(emb + (size_t)code * DIM + L * 4);
            // z from our own LDS: z = -(hi+lo)/2 (exact reconstruction)
            const char* zrow = smem + rl * 1040 + (L >> 1) * 16 + (L & 1) * 8;
            f16x4 hh = *(const f16x4*)(zrow);
            f16x4 ll = *(const f16x4*)(zrow + 512);
            float zx = -0.5f * ((float)hh[0] + (float)ll[0]);
            float zy = -0.5f * ((float)hh[1] + (float)ll[1]);
            float zz = -0.5f * ((float)hh[2] + (float)ll[2]);
            float zw = -0.5f * ((float)hh[3] + (float)ll[3]);
            float dx = ev.x - zx, dy = ev.y - zy;
            float dz = ev.z - zz, dw = ev.w - zw;
            lsum += dx * dx + dy * dy + dz * dz + dw * dw;
            *(float4*)(zq_out + (size_t)rg * DIM + L * 4) = ev;
        }
        #pragma unroll
        for (int off = 32; off > 0; off >>= 1) lsum += __shfl_down(lsum, off, 64);
        if (L == 0) atomicAdd(loss_out, lsum * (1.25f / (float)ZQ_ELEMS));
    }
}

extern "C" void kernel_launch(void* const* d_in, const int* in_sizes, int n_in,
                              void* d_out, int out_size, void* d_ws, size_t ws_size,
                              hipStream_t stream) {
    const float* z   = (const float*)d_in[0];
    const float* emb = (const float*)d_in[1];
    float* out  = (float*)d_out;
    float* zq   = out;
    float* loss = out + ZQ_ELEMS;
    float* idx  = out + ZQ_ELEMS + 1;

    char* ws = (char*)d_ws;
    _Float16* et = (_Float16*)(ws + WS_ET);
    u64*   pk    = (u64*)(ws + WS_PK);
    unsigned int* cn = (unsigned int*)(ws + WS_CNT);

    static bool attr_set = false;
    if (!attr_set) {
        hipFuncSetAttribute((const void*)vq_main,
                            hipFuncAttributeMaxDynamicSharedMemorySize, 141312);
        attr_set = true;
    }

    vq_prep<<<256, 256, 0, stream>>>(emb, et, pk, cn, loss);
    vq_main<<<512, 512, 141312, stream>>>(z, emb, et, pk, cn, zq, loss, idx);
}

// Round 10
// 333.101 us; speedup vs baseline: 1.0699x; 1.0699x over previous
//
#include <hip/hip_runtime.h>
#include <hip/hip_cooperative_groups.h>
#include <stdint.h>

namespace cg = cooperative_groups;

// z: [16,1024,256] fp32 -> N=16384 rows, D=256
// embedding: [8192,256] fp32 -> K=8192 codes
// out = [ z_q (4194304 f32) | loss (1 f32) | indices (16384 as f32) ]
#define N_ROWS   16384
#define DIM      256
#define N_CODES  8192
#define ZQ_ELEMS 4194304

typedef _Float16 f16x8 __attribute__((ext_vector_type(8)));
typedef _Float16 f16x4 __attribute__((ext_vector_type(4)));
typedef float    f32x16 __attribute__((ext_vector_type(16)));
typedef unsigned long long u64;

// ---- workspace (bytes): et 8.52 MB | pkeys 128 KB ----
// et layout in f16x8 units (16 B) — CONTIGUOUS PER SPLIT (L2-set-uniform):
//   hi plane: sp*65536 + ksg*4096 + cw*2 + h   (sp=code>>11, cw=code&2047)
//   lo plane: +262144
//   aug:      524288 + code  ({||e||^2_hi, ||e||^2_lo, 0...})
// pkeys: ONE u64 per row, merged across the 4 code-splits by atomicMin.
//
// R10: SINGLE cooperative kernel, 3 phases, 2 grid.sync()s. R6/R9 lesson:
// fusing the final so it runs CONCURRENTLY with other blocks' main loops
// evicts the L2-resident code panels (MfmaUtil 55->21/28). Phases must stay
// separated; grid.sync() gives that separation without the ~70 us of
// launch/serialization overhead the 3-launch pipeline paid around vq_final.
// Cross-XCD visibility of phase-1 et stores: one writer-side __threadfence
// per block (single wave, at the phase boundary where L2 has few dirty
// lines) before grid.sync(); phase-3 reads pkeys via no-op atomicMin
// (coherence-point read, R9-verified correct).
#define WS_ET  0
#define WS_PK  (8519680)

static __device__ __forceinline__ u64 packkey(float d, int c) {
    unsigned int u = __float_as_uint(d);
    u ^= ((unsigned int)((int)u >> 31)) | 0x80000000u;   // monotone float map
    return ((u64)u << 32) | (unsigned int)c;             // min => (dist, then idx)
}

// grid 256 = 64 rb x 4 sp (sp = blockIdx&3, XCD = blockIdx%8 -> one split/XCD,
// contiguous 2.1-MB panel L2-resident). 512 threads, 141,312 B dynamic LDS ->
// exactly 1 block/CU -> cooperative co-residency guaranteed (256 = 1 x 256 CU).
// Phase 2 = R5 main loop verbatim; each block runs panels rb and rb+64.
__global__ __launch_bounds__(512, 2)
void vq_fused(const float* __restrict__ z, const float* __restrict__ emb,
              _Float16* __restrict__ et, u64* __restrict__ pkeys,
              float* __restrict__ zq_out, float* __restrict__ loss_out,
              float* __restrict__ idx_out) {
    extern __shared__ char smem[];
    cg::grid_group grid = cg::this_grid();

    const int t = threadIdx.x, w = t >> 6, L = t & 63;
    const int lo5 = L & 31, hi1 = L >> 5;
    const int rb = blockIdx.x >> 2, sp = blockIdx.x & 3;
    const int codeS = sp * 2048;

    // ================= phase 1: prep (32 codes/block) + init =================
    {
        _Float16* shp = (_Float16*)smem;         // [2][32][272] halves (34,816 B)
        if (blockIdx.x == 0 && t == 0) *loss_out = 0.0f;
        if (t < 64) pkeys[blockIdx.x * 64 + t] = ~0ULL;
        const int code0 = blockIdx.x * 32;
        const int sp0 = code0 >> 11, cw0 = code0 & 2047;
        #pragma unroll
        for (int j = 0; j < 4; ++j) {
            const int cl = w * 4 + j;
            float4 v = *(const float4*)(emb + (size_t)(code0 + cl) * DIM + L * 4);
            float xs[4] = {v.x, v.y, v.z, v.w};
            f16x4 hh, lo;
            float s = 0.0f;
            #pragma unroll
            for (int i = 0; i < 4; ++i) {
                _Float16 h = (_Float16)xs[i];
                hh[i] = h;
                lo[i] = (_Float16)(xs[i] - (float)h);
                s += xs[i] * xs[i];
            }
            *(f16x4*)&shp[cl * 272 + L * 4] = hh;
            *(f16x4*)&shp[8704 + cl * 272 + L * 4] = lo;
            #pragma unroll
            for (int off = 32; off > 0; off >>= 1) s += __shfl_down(s, off, 64);
            if (L == 0) {                        // aug: {norm_hi, norm_lo, 0..}
                _Float16 nh = (_Float16)s;
                _Float16 nl = (_Float16)(s - (float)nh);
                f16x8 aug;
                #pragma unroll
                for (int i = 0; i < 8; ++i) aug[i] = (_Float16)0;
                aug[0] = nh; aug[1] = nl;
                *(f16x8*)(et + ((size_t)524288 + code0 + cl) * 8) = aug;
            }
        }
        __syncthreads();
        #pragma unroll
        for (int pp = 0; pp < 4; ++pp) {         // 2048 units, coalesced stores
            const int gi = pp * 512 + t;
            const int p = gi >> 10, ks = (gi >> 6) & 15, cl = (gi >> 1) & 31, h = gi & 1;
            f16x8 frag = *(const f16x8*)&shp[p * 8704 + cl * 272 + ks * 16 + h * 8];
            const size_t unit = (size_t)p * 262144 + (size_t)sp0 * 65536
                              + (size_t)ks * 4096 + (size_t)(cw0 + cl) * 2 + h;
            *(f16x8*)(et + unit * 8) = frag;
        }
        __syncthreads();                         // all stores drained to L2
        if (w == 0) __threadfence();             // ONE wave: L2 writeback -> L3
    }
    grid.sync();

    // ================= phase 2: main (R5 loop), 2 panels/block =================
    u64* run = (u64*)(smem + 133120);            // [8][128]

    f16x8 bz;                                    // aug B: B[k0]=B[k1]=1 (hi1=0), else 0
    #pragma unroll
    for (int i = 0; i < 8; ++i) bz[i] = (_Float16)0;
    if (hi1 == 0) { bz[0] = (_Float16)1; bz[1] = (_Float16)1; }

    f32x16 zacc;                                 // constant C=0 for aug MFMAs
    #pragma unroll
    for (int e = 0; e < 16; ++e) zacc[e] = 0.0f;

    const f16x8* eb  = (const f16x8*)et;
    const f16x8* ebL = eb + 262144;              // lo plane
    const int laneU = lo5 * 2 + hi1;             // loop-invariant A voffset (units)
    const size_t spB = (size_t)sp * 65536;
    const char* zbA = smem + (lo5 * 1040 + hi1 * 16);
    const char* zbB = zbA + 66560;               // rows 64..127 (imm stays < 64 KB)

    for (int pi = 0; pi < 2; ++pi) {
        const int row0 = (rb + 64 * pi) * 128;
        __syncthreads();                         // prior readers done before overwrite

        // ---- stage z: coalesced f32 loads -> (-2z) hi/lo -> lane-linear ds_write ----
        const float* zr = z + (size_t)row0 * DIM;
        #pragma unroll
        for (int jj = 0; jj < 16; ++jj) {
            const int idx = jj * 512 + t;        // float4 index in [0,8192)
            const int r = idx >> 6, q = idx & 63;
            float4 v = *(const float4*)(zr + (size_t)r * DIM + q * 4);
            float xs[4] = {v.x, v.y, v.z, v.w};
            f16x4 hh, lo;
            #pragma unroll
            for (int i = 0; i < 4; ++i) {
                const float m2 = -2.0f * xs[i];  // planes carry -2z
                _Float16 h = (_Float16)m2;
                hh[i] = h;
                lo[i] = (_Float16)(m2 - (float)h);
            }
            char* base = smem + r * 1040 + q * 8;
            *(f16x4*)(base) = hh;                // hi plane
            *(f16x4*)(base + 512) = lo;          // lo plane
        }
        run[t] = ~0ULL;
        run[t + 512] = ~0ULL;

        // prefetch aug-A for ci=0 and A ksg=0 (overlap staging + barrier)
        f16x8 paug[2];
        {
            const int c0 = codeS + w * 64;
            paug[0] = eb[(size_t)524288 + c0 + lo5];
            paug[1] = eb[(size_t)524288 + c0 + 32 + lo5];
        }
        f16x8 aC0, aC1, aC2, aC3;
        {
            const size_t cu = spB + (size_t)(w * 64) * 2 + laneU;
            aC0 = eb[cu]; aC1 = eb[cu + 64]; aC2 = ebL[cu]; aC3 = ebL[cu + 64];
        }
        __syncthreads();

        for (int ci = 0; ci < 4; ++ci) {
            const int c0 = codeS + ci * 512 + w * 64;
            const size_t cu = spB + (size_t)(ci * 512 + w * 64) * 2 + laneU;
            f32x16 acc[2][4];

            // aug-first: acc = ||e||^2 broadcast (also the zero-init)
            __builtin_amdgcn_s_setprio(1);
            #pragma unroll
            for (int mt = 0; mt < 2; ++mt)
                #pragma unroll
                for (int nt = 0; nt < 4; ++nt)
                    acc[mt][nt] = __builtin_amdgcn_mfma_f32_32x32x16_f16(paug[mt], bz, zacc, 0, 0, 0);
            __builtin_amdgcn_s_setprio(0);

            if (ci < 3) {                        // prefetch aug-A for ci+1
                const int c1 = codeS + (ci + 1) * 512 + w * 64;
                paug[0] = eb[(size_t)524288 + c1 + lo5];
                paug[1] = eb[(size_t)524288 + c1 + 32 + lo5];
            }

            #pragma unroll 4
            for (int ksg = 0; ksg < 16; ++ksg) {
                // A prefetch for ksg+1 (ksg=15 -> phantom, in-bounds, unused)
                const size_t ubn = cu + (size_t)(ksg + 1) * 4096;
                f16x8 aN0 = eb[ubn], aN1 = eb[ubn + 64];
                f16x8 aN2 = ebL[ubn], aN3 = ebL[ubn + 64];

                {
                    f16x8 bh0 = *(const f16x8*)(zbA + (ksg * 32));
                    f16x8 bl0 = *(const f16x8*)(zbA + (ksg * 32 + 512));
                    f16x8 bh1 = *(const f16x8*)(zbA + (ksg * 32 + 33280));
                    f16x8 bl1 = *(const f16x8*)(zbA + (ksg * 32 + 33280 + 512));
                    __builtin_amdgcn_s_setprio(1);
                    acc[0][0] = __builtin_amdgcn_mfma_f32_32x32x16_f16(aC0, bh0, acc[0][0], 0, 0, 0);
                    acc[0][0] = __builtin_amdgcn_mfma_f32_32x32x16_f16(aC0, bl0, acc[0][0], 0, 0, 0);
                    acc[0][0] = __builtin_amdgcn_mfma_f32_32x32x16_f16(aC2, bh0, acc[0][0], 0, 0, 0);
                    acc[0][1] = __builtin_amdgcn_mfma_f32_32x32x16_f16(aC0, bh1, acc[0][1], 0, 0, 0);
                    acc[0][1] = __builtin_amdgcn_mfma_f32_32x32x16_f16(aC0, bl1, acc[0][1], 0, 0, 0);
                    acc[0][1] = __builtin_amdgcn_mfma_f32_32x32x16_f16(aC2, bh1, acc[0][1], 0, 0, 0);
                    acc[1][0] = __builtin_amdgcn_mfma_f32_32x32x16_f16(aC1, bh0, acc[1][0], 0, 0, 0);
                    acc[1][0] = __builtin_amdgcn_mfma_f32_32x32x16_f16(aC1, bl0, acc[1][0], 0, 0, 0);
                    acc[1][0] = __builtin_amdgcn_mfma_f32_32x32x16_f16(aC3, bh0, acc[1][0], 0, 0, 0);
                    acc[1][1] = __builtin_amdgcn_mfma_f32_32x32x16_f16(aC1, bh1, acc[1][1], 0, 0, 0);
                    acc[1][1] = __builtin_amdgcn_mfma_f32_32x32x16_f16(aC1, bl1, acc[1][1], 0, 0, 0);
                    acc[1][1] = __builtin_amdgcn_mfma_f32_32x32x16_f16(aC3, bh1, acc[1][1], 0, 0, 0);
                    __builtin_amdgcn_s_setprio(0);
                }
                {
                    f16x8 bh2 = *(const f16x8*)(zbB + (ksg * 32));
                    f16x8 bl2 = *(const f16x8*)(zbB + (ksg * 32 + 512));
                    f16x8 bh3 = *(const f16x8*)(zbB + (ksg * 32 + 33280));
                    f16x8 bl3 = *(const f16x8*)(zbB + (ksg * 32 + 33280 + 512));
                    __builtin_amdgcn_s_setprio(1);
                    acc[0][2] = __builtin_amdgcn_mfma_f32_32x32x16_f16(aC0, bh2, acc[0][2], 0, 0, 0);
                    acc[0][2] = __builtin_amdgcn_mfma_f32_32x32x16_f16(aC0, bl2, acc[0][2], 0, 0, 0);
                    acc[0][2] = __builtin_amdgcn_mfma_f32_32x32x16_f16(aC2, bh2, acc[0][2], 0, 0, 0);
                    acc[0][3] = __builtin_amdgcn_mfma_f32_32x32x16_f16(aC0, bh3, acc[0][3], 0, 0, 0);
                    acc[0][3] = __builtin_amdgcn_mfma_f32_32x32x16_f16(aC0, bl3, acc[0][3], 0, 0, 0);
                    acc[0][3] = __builtin_amdgcn_mfma_f32_32x32x16_f16(aC2, bh3, acc[0][3], 0, 0, 0);
                    acc[1][2] = __builtin_amdgcn_mfma_f32_32x32x16_f16(aC1, bh2, acc[1][2], 0, 0, 0);
                    acc[1][2] = __builtin_amdgcn_mfma_f32_32x32x16_f16(aC1, bl2, acc[1][2], 0, 0, 0);
                    acc[1][2] = __builtin_amdgcn_mfma_f32_32x32x16_f16(aC3, bh2, acc[1][2], 0, 0, 0);
                    acc[1][3] = __builtin_amdgcn_mfma_f32_32x32x16_f16(aC1, bh3, acc[1][3], 0, 0, 0);
                    acc[1][3] = __builtin_amdgcn_mfma_f32_32x32x16_f16(aC1, bl3, acc[1][3], 0, 0, 0);
                    acc[1][3] = __builtin_amdgcn_mfma_f32_32x32x16_f16(aC3, bh3, acc[1][3], 0, 0, 0);
                    __builtin_amdgcn_s_setprio(0);
                }
                aC0 = aN0; aC1 = aN1; aC2 = aN2; aC3 = aN3;
            }

            // prefetch A ksg=0 of next ci BEFORE the fold
            {
                const size_t cuN = spB + (size_t)((((ci + 1) & 3) * 512) + w * 64) * 2 + laneU;
                aC0 = eb[cuN]; aC1 = eb[cuN + 64]; aC2 = ebL[cuN]; aC3 = ebL[cuN + 64];
            }

            // ---- fold: f32 min-tree + first-match index, one packkey per nt ----
            #pragma unroll
            for (int nt = 0; nt < 4; ++nt) {
                float mm[16];
                #pragma unroll
                for (int r = 0; r < 16; ++r)
                    mm[r] = fminf(acc[0][nt][r], acc[1][nt][r]);
                #pragma unroll
                for (int s2 = 8; s2 > 0; s2 >>= 1)
                    #pragma unroll
                    for (int r = 0; r < 8; ++r)
                        if (r < s2) mm[r] = fminf(mm[r], mm[r + s2]);
                const float m = mm[0];
                int rel = 64;                    // sentinel; rc max 59
                #pragma unroll
                for (int mt = 0; mt < 2; ++mt)
                    #pragma unroll
                    for (int r = 0; r < 16; ++r) {
                        const int rc = mt * 32 + (r & 3) + 8 * (r >> 2);
                        const int cand = (acc[mt][nt][r] == m) ? rc : 64;
                        rel = cand < rel ? cand : rel;   // lowest code wins
                    }
                u64 best = packkey(m, c0 + 4 * hi1 + rel);
                const u64 o = __shfl_xor(best, 32, 64);  // merge code-halves
                if (o < best) best = o;
                if (hi1 == 0) {
                    u64* p = &run[w * 128 + nt * 32 + lo5];  // sole writer
                    if (best < *p) *p = best;
                }
            }
        }

        __syncthreads();
        if (t < 128) {                           // merge 8 waves, then cross-split
            u64 k = run[t];
            #pragma unroll
            for (int w2 = 1; w2 < 8; ++w2) { u64 o = run[w2 * 128 + t]; if (o < k) k = o; }
            atomicMin(&pkeys[row0 + t], k);      // device-scope, coherence point
        }
    }
    grid.sync();

    // ================= phase 3: distributed final (64 rows/block) =================
    {
        int* bestc = (int*)(smem + 133120);
        float* wsum = (float*)(smem + 137216);
        // rows: rb*128 + sp*32 + [0,32)  and  + 8192 (the block's two panels)
        if (t < 64) {
            const int gr = ((t < 32) ? rb * 128 : 8192 + rb * 128) + sp * 32 + (t & 31);
            const u64 k = atomicMin(&pkeys[gr], ~0ULL);  // coherence-point read
            const int code = (int)(k & 0xFFFFFFFFu);
            bestc[t] = code;
            idx_out[gr] = (float)code;
        }
        __syncthreads();
        float lsum = 0.0f;
        #pragma unroll
        for (int rr = 0; rr < 8; ++rr) {
            const int rl = w * 8 + rr;
            const int gr = ((rl < 32) ? rb * 128 : 8192 + rb * 128) + sp * 32 + (rl & 31);
            const int code = bestc[rl];
            float4 ev = *(const float4*)(emb + (size_t)code * DIM + L * 4);
            float4 zv = *(const float4*)(z   + (size_t)gr   * DIM + L * 4);
            float dx = ev.x - zv.x, dy = ev.y - zv.y;
            float dz = ev.z - zv.z, dw = ev.w - zv.w;
            lsum += dx * dx + dy * dy + dz * dz + dw * dw;
            *(float4*)(zq_out + (size_t)gr * DIM + L * 4) = ev;
        }
        #pragma unroll
        for (int off = 32; off > 0; off >>= 1) lsum += __shfl_down(lsum, off, 64);
        if (L == 0) wsum[w] = lsum;
        __syncthreads();
        if (t == 0) {
            float s = 0.0f;
            #pragma unroll
            for (int i = 0; i < 8; ++i) s += wsum[i];
            atomicAdd(loss_out, s * (1.25f / (float)ZQ_ELEMS));  // 1 atomic/block
        }
    }
}

extern "C" void kernel_launch(void* const* d_in, const int* in_sizes, int n_in,
                              void* d_out, int out_size, void* d_ws, size_t ws_size,
                              hipStream_t stream) {
    const float* z   = (const float*)d_in[0];
    const float* emb = (const float*)d_in[1];
    float* out  = (float*)d_out;
    float* zq   = out;
    float* loss = out + ZQ_ELEMS;
    float* idx  = out + ZQ_ELEMS + 1;

    char* ws = (char*)d_ws;
    _Float16* et = (_Float16*)(ws + WS_ET);
    u64*   pk    = (u64*)(ws + WS_PK);

    static bool attr_set = false;
    if (!attr_set) {
        hipFuncSetAttribute((const void*)vq_fused,
                            hipFuncAttributeMaxDynamicSharedMemorySize, 141312);
        attr_set = true;
    }

    void* args[] = {(void*)&z, (void*)&emb, (void*)&et, (void*)&pk,
                    (void*)&zq, (void*)&loss, (void*)&idx};
    hipLaunchCooperativeKernel((const void*)vq_fused, dim3(256), dim3(512),
                               args, 141312, stream);
}

// Round 11
// 262.899 us; speedup vs baseline: 1.3556x; 1.2670x over previous
//
#include <hip/hip_runtime.h>
#include <stdint.h>

// z: [16,1024,256] fp32 -> N=16384 rows, D=256
// embedding: [8192,256] fp32 -> K=8192 codes
// out = [ z_q (4194304 f32) | loss (1 f32) | indices (16384 as f32) ]
#define N_ROWS   16384
#define DIM      256
#define N_CODES  8192
#define ZQ_ELEMS 4194304

typedef _Float16 f16x8 __attribute__((ext_vector_type(8)));
typedef _Float16 f16x4 __attribute__((ext_vector_type(4)));
typedef float    f32x16 __attribute__((ext_vector_type(16)));
typedef unsigned long long u64;

// ---- workspace (bytes): et 8.52 MB | pkeys 128 KB ----
// et layout in f16x8 units (16 B) — CONTIGUOUS PER SPLIT (L2-set-uniform):
//   hi plane: sp*65536 + ksg*4096 + cw*2 + h   (sp=code>>11, cw=code&2047)
//   lo plane: +262144
//   aug:      524288 + code  ({||e||^2_hi, ||e||^2_lo, 0...})
// pkeys: ONE u64 per row, merged across the 4 code-splits by atomicMin.
//   KEY NOW CARRIES THE TRUE DISTANCE: fold packs (||z||^2 + ||e||^2 - 2z.e);
//   ||z||^2 (f32, computed during staging) is constant per row -> argmin
//   unchanged, but vq_final can decode loss directly from pkeys and never
//   re-read z (final was ~55 us of the old 99-us non-main time).
// R11 main: mt=1/nt=4/8ci — same MFMA:A-load ratio (6:1) as R5 but acc=64
// AGPR, freeing registers to software-pipeline BOTH A and B one full body
// ahead (R5 covered A only; B's 8 ds_read_b128 were latency-exposed).
#define WS_ET  0
#define WS_PK  (8519680)

static __device__ __forceinline__ u64 packkey(float d, int c) {
    unsigned int u = __float_as_uint(d);
    u ^= ((unsigned int)((int)u >> 31)) | 0x80000000u;   // monotone float map
    return ((u64)u << 32) | (unsigned int)c;             // min => (dist, then idx)
}

#define MFMA16(a, b, c) __builtin_amdgcn_mfma_f32_32x32x16_f16((a), (b), (c), 0, 0, 0)

// ---------------- prep: e-only, 256 fat blocks x 32 codes; init pkeys ----------------
__global__ void vq_prep(const float* __restrict__ emb, _Float16* __restrict__ et,
                        u64* __restrict__ pkeys, float* __restrict__ loss_ptr) {
    __shared__ _Float16 sh[2][32][272];          // 34,816 B (272-stride: conflict-free)
    const int t = threadIdx.x, w = t >> 6, l = t & 63;
    if (blockIdx.x == 0 && t == 0) *loss_ptr = 0.0f;
    if (t < 64) pkeys[blockIdx.x * 64 + t] = ~0ULL;
    const int code0 = blockIdx.x * 32;
    const int sp0 = code0 >> 11, cw0 = code0 & 2047;   // block never straddles a split
    #pragma unroll
    for (int j = 0; j < 8; ++j) {
        const int cl = w * 8 + j;
        float4 v = *(const float4*)(emb + (size_t)(code0 + cl) * DIM + l * 4);
        float xs[4] = {v.x, v.y, v.z, v.w};
        f16x4 hh, lo;
        float s = 0.0f;
        #pragma unroll
        for (int i = 0; i < 4; ++i) {
            _Float16 h = (_Float16)xs[i];
            hh[i] = h;
            lo[i] = (_Float16)(xs[i] - (float)h);
            s += xs[i] * xs[i];
        }
        *(f16x4*)&sh[0][cl][l * 4] = hh;
        *(f16x4*)&sh[1][cl][l * 4] = lo;
        #pragma unroll
        for (int off = 32; off > 0; off >>= 1) s += __shfl_down(s, off, 64);
        if (l == 0) {                            // aug: {norm_hi, norm_lo, 0..}
            _Float16 nh = (_Float16)s;
            _Float16 nl = (_Float16)(s - (float)nh);
            f16x8 aug;
            #pragma unroll
            for (int i = 0; i < 8; ++i) aug[i] = (_Float16)0;
            aug[0] = nh; aug[1] = nl;
            *(f16x8*)(et + ((size_t)524288 + code0 + cl) * 8) = aug;
        }
    }
    __syncthreads();
    #pragma unroll
    for (int pp = 0; pp < 8; ++pp) {             // 2048 units, 1-KB coalesced stores
        const int gi = pp * 256 + t;
        const int p = gi >> 10, ks = (gi >> 6) & 15, cl = (gi >> 1) & 31, h = gi & 1;
        f16x8 frag = *(const f16x8*)&sh[p][cl][ks * 16 + h * 8];
        const size_t unit = (size_t)p * 262144 + (size_t)sp0 * 65536
                          + (size_t)ks * 4096 + (size_t)(cw0 + cl) * 2 + h;
        *(f16x8*)(et + unit * 8) = frag;
    }
}

// ---------------- main: 128-row blocks, 4-way XCD-pinned split; A+B pipelined ----------------
// grid 512 = 128 rb x 4 sp; sp = blockIdx&3 (XCD = %8 -> one split per XCD,
// contiguous 2.1-MB panel L2-resident). 512 threads (8 waves, 2/SIMD, 1 blk/CU).
// mt=1, nt=4, 8 ci: 12 MFMA per {2 A-frag loads + 8 B ds_reads}; acc = 4 x
// f32x16 = 64 AGPR, so both A(ksg+1) and B((ksg+1)&15) are prefetched a full
// body ahead (~100 cyc MFMA cover). B wrap makes ci-boundary prefetch free.
// LDS: z 133,120 | run 8,192 | zn 512 = 141,824 B.
__global__ __launch_bounds__(512, 2)
void vq_main(const float* __restrict__ z, const _Float16* __restrict__ et,
             u64* __restrict__ pkeys) {
    extern __shared__ char smem[];
    u64* run = (u64*)(smem + 133120);            // [8][128]
    float* zn = (float*)(smem + 141312);         // [128] ||z_row||^2

    const int tid = threadIdx.x;
    const int w = tid >> 6, L = tid & 63, lo5 = L & 31, hi1 = L >> 5;
    const int rb = blockIdx.x >> 2, sp = blockIdx.x & 3;
    const int row0 = rb * 128, codeS = sp * 2048;

    // ---- stage z: f32 loads -> (-2z) hi/lo ds_write; wave-reduce ||z||^2 ----
    const float* zr = z + (size_t)row0 * DIM;
    #pragma unroll
    for (int jj = 0; jj < 16; ++jj) {
        const int idx = jj * 512 + tid;          // float4 index in [0,8192)
        const int r = idx >> 6, q = idx & 63;    // r = jj*8 + w, q = L
        float4 v = *(const float4*)(zr + (size_t)r * DIM + q * 4);
        float xs[4] = {v.x, v.y, v.z, v.w};
        float ss = xs[0]*xs[0] + xs[1]*xs[1] + xs[2]*xs[2] + xs[3]*xs[3];
        f16x4 hh, lo;
        #pragma unroll
        for (int i = 0; i < 4; ++i) {
            const float m2 = -2.0f * xs[i];      // planes carry -2z
            _Float16 h = (_Float16)m2;
            hh[i] = h;
            lo[i] = (_Float16)(m2 - (float)h);
        }
        char* base = smem + r * 1040 + q * 8;
        *(f16x4*)(base) = hh;                    // hi plane
        *(f16x4*)(base + 512) = lo;              // lo plane
        #pragma unroll
        for (int off = 32; off > 0; off >>= 1) ss += __shfl_down(ss, off, 64);
        if (L == 0) zn[r] = ss;                  // row norm (f32, exact-ish)
    }
    run[tid] = ~0ULL;
    run[tid + 512] = ~0ULL;

    f16x8 bz;                                    // aug B: B[k0]=B[k1]=1 (hi1=0), else 0
    #pragma unroll
    for (int i = 0; i < 8; ++i) bz[i] = (_Float16)0;
    if (hi1 == 0) { bz[0] = (_Float16)1; bz[1] = (_Float16)1; }

    f32x16 zacc;                                 // constant C=0 for aug MFMAs
    #pragma unroll
    for (int e = 0; e < 16; ++e) zacc[e] = 0.0f;

    const f16x8* eb  = (const f16x8*)et;
    const f16x8* ebL = eb + 262144;              // lo plane
    const int laneU = lo5 * 2 + hi1;             // loop-invariant A voffset (units)
    const size_t spB = (size_t)sp * 65536;
    const char* zbA = smem + (lo5 * 1040 + hi1 * 16);
    const char* zbB = zbA + 66560;               // rows 64..127 (imm stays < 64 KB)

    // prologue: paug(ci=0), A(ci=0, ksg=0)
    f16x8 paug = eb[(size_t)524288 + codeS + w * 32 + lo5];
    f16x8 ahC, alC;
    {
        const size_t cu0 = spB + (size_t)(w * 64 + laneU);
        ahC = eb[cu0]; alC = ebL[cu0];
    }
    __syncthreads();
    // prologue: B(ksg=0)
    f16x8 b0h = *(const f16x8*)(zbA);
    f16x8 b0l = *(const f16x8*)(zbA + 512);
    f16x8 b1h = *(const f16x8*)(zbA + 33280);
    f16x8 b1l = *(const f16x8*)(zbA + 33280 + 512);
    f16x8 b2h = *(const f16x8*)(zbB);
    f16x8 b2l = *(const f16x8*)(zbB + 512);
    f16x8 b3h = *(const f16x8*)(zbB + 33280);
    f16x8 b3l = *(const f16x8*)(zbB + 33280 + 512);

    for (int ci = 0; ci < 8; ++ci) {
        const int c0 = codeS + ci * 256 + w * 32;
        const size_t cu = spB + (size_t)(ci * 512 + w * 64 + laneU);
        f32x16 acc[4];

        // aug-first: acc = ||e||^2 broadcast (also the zero-init)
        __builtin_amdgcn_s_setprio(1);
        #pragma unroll
        for (int nt = 0; nt < 4; ++nt)
            acc[nt] = MFMA16(paug, bz, zacc);
        __builtin_amdgcn_s_setprio(0);

        if (ci < 7)                              // prefetch aug-A for ci+1
            paug = eb[(size_t)524288 + c0 + 256 + lo5];

        #pragma unroll 4
        for (int ksg = 0; ksg < 16; ++ksg) {
            // next-body prefetch: A wraps to next ci at ksg=15; B wraps &15
            const size_t ubn = (ksg < 15)
                ? (cu + (size_t)(ksg + 1) * 4096)
                : (spB + (size_t)((((ci + 1) & 7) * 512) + w * 64 + laneU));
            f16x8 ahN = eb[ubn], alN = ebL[ubn];
            const int ko = ((ksg + 1) & 15) * 32;
            f16x8 b0hN = *(const f16x8*)(zbA + ko);
            f16x8 b0lN = *(const f16x8*)(zbA + ko + 512);
            f16x8 b1hN = *(const f16x8*)(zbA + ko + 33280);
            f16x8 b1lN = *(const f16x8*)(zbA + ko + 33280 + 512);
            f16x8 b2hN = *(const f16x8*)(zbB + ko);
            f16x8 b2lN = *(const f16x8*)(zbB + ko + 512);
            f16x8 b3hN = *(const f16x8*)(zbB + ko + 33280);
            f16x8 b3lN = *(const f16x8*)(zbB + ko + 33280 + 512);

            __builtin_amdgcn_s_setprio(1);
            acc[0] = MFMA16(ahC, b0h, acc[0]);
            acc[0] = MFMA16(ahC, b0l, acc[0]);
            acc[0] = MFMA16(alC, b0h, acc[0]);
            acc[1] = MFMA16(ahC, b1h, acc[1]);
            acc[1] = MFMA16(ahC, b1l, acc[1]);
            acc[1] = MFMA16(alC, b1h, acc[1]);
            acc[2] = MFMA16(ahC, b2h, acc[2]);
            acc[2] = MFMA16(ahC, b2l, acc[2]);
            acc[2] = MFMA16(alC, b2h, acc[2]);
            acc[3] = MFMA16(ahC, b3h, acc[3]);
            acc[3] = MFMA16(ahC, b3l, acc[3]);
            acc[3] = MFMA16(alC, b3h, acc[3]);
            __builtin_amdgcn_s_setprio(0);

            ahC = ahN; alC = alN;
            b0h = b0hN; b0l = b0lN; b1h = b1hN; b1l = b1lN;
            b2h = b2hN; b2l = b2lN; b3h = b3hN; b3l = b3lN;
        }
        // (A ksg0 of ci+1 and B ksg0 already live in ahC/alC/b*h/b*l via wrap)

        // ---- fold: min-tree + first-match index; pack TRUE distance (+||z||^2) ----
        #pragma unroll
        for (int nt = 0; nt < 4; ++nt) {
            float mm[16];
            #pragma unroll
            for (int r = 0; r < 16; ++r) mm[r] = acc[nt][r];
            #pragma unroll
            for (int s2 = 8; s2 > 0; s2 >>= 1)
                #pragma unroll
                for (int r = 0; r < 8; ++r)
                    if (r < s2) mm[r] = fminf(mm[r], mm[r + s2]);
            const float m = mm[0];
            int rel = 64;                        // sentinel; rc max 27
            #pragma unroll
            for (int r = 0; r < 16; ++r) {
                const int rc = (r & 3) + 8 * (r >> 2);
                const int cand = (acc[nt][r] == m) ? rc : 64;
                rel = cand < rel ? cand : rel;   // monotone rc => lowest code wins
            }
            const float zrow = zn[nt * 32 + lo5];    // this lane's z-row norm
            u64 best = packkey(m + zrow, c0 + 4 * hi1 + rel);
            const u64 o = __shfl_xor(best, 32, 64);  // merge code-halves (same row)
            if (o < best) best = o;
            if (hi1 == 0) {
                u64* p = &run[w * 128 + nt * 32 + lo5];  // sole writer per slot
                if (best < *p) *p = best;
            }
        }
    }

    __syncthreads();
    if (tid < 128) {                             // merge 8 waves, then cross-split
        u64 k = run[tid];
        #pragma unroll
        for (int w2 = 1; w2 < 8; ++w2) { u64 o = run[w2 * 128 + tid]; if (o < k) k = o; }
        atomicMin(&pkeys[row0 + tid], k);
    }
}

// ---------------- final: idx + loss decoded from pkeys; e-gather -> z_q ----------------
// No z read: key's hi word IS the (monotone-mapped) true distance ||z-e||^2.
__global__ __launch_bounds__(256)
void vq_final(const float* __restrict__ emb, const u64* __restrict__ pkeys,
              float* __restrict__ zq_out, float* __restrict__ loss_out,
              float* __restrict__ idx_out) {
    __shared__ int bestc[64];
    const int t = threadIdx.x;
    const int row0 = blockIdx.x * 64;
    if (t < 64) {                                // wave 0
        const u64 k = pkeys[row0 + t];
        const int code = (int)(k & 0xFFFFFFFFu);
        unsigned int mu = (unsigned int)(k >> 32);
        mu = (mu & 0x80000000u) ? (mu ^ 0x80000000u) : ~mu;  // inverse monotone map
        float d = __uint_as_float(mu);
        bestc[t] = code;
        idx_out[row0 + t] = (float)code;
        #pragma unroll
        for (int off = 32; off > 0; off >>= 1) d += __shfl_down(d, off, 64);
        if (t == 0) atomicAdd(loss_out, d * (1.25f / (float)ZQ_ELEMS));
    }
    __syncthreads();
    const int wave = t >> 6, lane = t & 63;      // 4 waves x 16 rows
    #pragma unroll
    for (int rr = 0; rr < 16; ++rr) {
        const int rl = wave * 16 + rr;
        const int code = bestc[rl];
        float4 ev = *(const float4*)(emb + (size_t)code * DIM + lane * 4);
        *(float4*)(zq_out + (size_t)(row0 + rl) * DIM + lane * 4) = ev;
    }
}

extern "C" void kernel_launch(void* const* d_in, const int* in_sizes, int n_in,
                              void* d_out, int out_size, void* d_ws, size_t ws_size,
                              hipStream_t stream) {
    const float* z   = (const float*)d_in[0];
    const float* emb = (const float*)d_in[1];
    float* out  = (float*)d_out;
    float* zq   = out;
    float* loss = out + ZQ_ELEMS;
    float* idx  = out + ZQ_ELEMS + 1;

    char* ws = (char*)d_ws;
    _Float16* et = (_Float16*)(ws + WS_ET);
    u64*   pk    = (u64*)(ws + WS_PK);

    static bool attr_set = false;
    if (!attr_set) {
        hipFuncSetAttribute((const void*)vq_main,
                            hipFuncAttributeMaxDynamicSharedMemorySize, 141824);
        attr_set = true;
    }

    vq_prep<<<256, 256, 0, stream>>>(emb, et, pk, loss);
    vq_main<<<512, 512, 141824, stream>>>(z, et, pk);
    vq_final<<<N_ROWS / 64, 256, 0, stream>>>(emb, pk, zq, loss, idx);
}

// Round 12
// 252.556 us; speedup vs baseline: 1.4111x; 1.0410x over previous
//
#include <hip/hip_runtime.h>
#include <stdint.h>

// z: [16,1024,256] fp32 -> N=16384 rows, D=256
// embedding: [8192,256] fp32 -> K=8192 codes
// out = [ z_q (4194304 f32) | loss (1 f32) | indices (16384 as f32) ]
#define N_ROWS   16384
#define DIM      256
#define N_CODES  8192
#define ZQ_ELEMS 4194304

typedef _Float16 f16x8 __attribute__((ext_vector_type(8)));
typedef _Float16 f16x4 __attribute__((ext_vector_type(4)));
typedef float    f32x16 __attribute__((ext_vector_type(16)));
typedef unsigned long long u64;

// ---- workspace (bytes): et 8.52 MB | pkeys 128 KB ----
// et layout in f16x8 units (16 B) — CONTIGUOUS PER SPLIT (L2-set-uniform):
//   hi plane: sp*65536 + ksg*4096 + cw*2 + h   (sp=code>>11, cw=code&2047)
//   lo plane: +262144
//   aug:      524288 + code  ({||e||^2_hi, ||e||^2_lo, 0...})
// pkeys: ONE u64 per row, merged across the 4 code-splits by atomicMin.
//   Key carries the TRUE distance (||z||^2 + ||e||^2 - 2z.e): ||z||^2 is
//   per-row constant (argmin unchanged) and lets vq_final decode the loss
//   from pkeys without re-reading z (R11-verified, saved ~26 us).
// R12 = recombination: R5's main loop (mt=2/nt=4, A-only dbuf — 175 us,
// beats R11's mt=1 A+B pipeline at 190 us: halving A-reuse cost more than
// B-latency cover bought) + R11's zn/key/final.
#define WS_ET  0
#define WS_PK  (8519680)

static __device__ __forceinline__ u64 packkey(float d, int c) {
    unsigned int u = __float_as_uint(d);
    u ^= ((unsigned int)((int)u >> 31)) | 0x80000000u;   // monotone float map
    return ((u64)u << 32) | (unsigned int)c;             // min => (dist, then idx)
}

// ---------------- prep: e-only, 256 fat blocks x 32 codes; init pkeys ----------------
__global__ void vq_prep(const float* __restrict__ emb, _Float16* __restrict__ et,
                        u64* __restrict__ pkeys, float* __restrict__ loss_ptr) {
    __shared__ _Float16 sh[2][32][272];          // 34,816 B (272-stride: conflict-free)
    const int t = threadIdx.x, w = t >> 6, l = t & 63;
    if (blockIdx.x == 0 && t == 0) *loss_ptr = 0.0f;
    if (t < 64) pkeys[blockIdx.x * 64 + t] = ~0ULL;
    const int code0 = blockIdx.x * 32;
    const int sp0 = code0 >> 11, cw0 = code0 & 2047;   // block never straddles a split
    #pragma unroll
    for (int j = 0; j < 8; ++j) {
        const int cl = w * 8 + j;
        float4 v = *(const float4*)(emb + (size_t)(code0 + cl) * DIM + l * 4);
        float xs[4] = {v.x, v.y, v.z, v.w};
        f16x4 hh, lo;
        float s = 0.0f;
        #pragma unroll
        for (int i = 0; i < 4; ++i) {
            _Float16 h = (_Float16)xs[i];
            hh[i] = h;
            lo[i] = (_Float16)(xs[i] - (float)h);
            s += xs[i] * xs[i];
        }
        *(f16x4*)&sh[0][cl][l * 4] = hh;
        *(f16x4*)&sh[1][cl][l * 4] = lo;
        #pragma unroll
        for (int off = 32; off > 0; off >>= 1) s += __shfl_down(s, off, 64);
        if (l == 0) {                            // aug: {norm_hi, norm_lo, 0..}
            _Float16 nh = (_Float16)s;
            _Float16 nl = (_Float16)(s - (float)nh);
            f16x8 aug;
            #pragma unroll
            for (int i = 0; i < 8; ++i) aug[i] = (_Float16)0;
            aug[0] = nh; aug[1] = nl;
            *(f16x8*)(et + ((size_t)524288 + code0 + cl) * 8) = aug;
        }
    }
    __syncthreads();
    #pragma unroll
    for (int pp = 0; pp < 8; ++pp) {             // 2048 units, 1-KB coalesced stores
        const int gi = pp * 256 + t;
        const int p = gi >> 10, ks = (gi >> 6) & 15, cl = (gi >> 1) & 31, h = gi & 1;
        f16x8 frag = *(const f16x8*)&sh[p][cl][ks * 16 + h * 8];
        const size_t unit = (size_t)p * 262144 + (size_t)sp0 * 65536
                          + (size_t)ks * 4096 + (size_t)(cw0 + cl) * 2 + h;
        *(f16x8*)(et + unit * 8) = frag;
    }
}

// ---------------- main: 128-row blocks, 4-way XCD-pinned code split ----------------
// grid 512 = 128 rb x 4 sp; sp = blockIdx&3 (XCD = %8 -> one split per XCD;
// contiguous 2.1-MB panel L2-resident). 512 threads (8 waves, 2/SIMD, 1 blk/CU).
// A = e from global with one-ksg-ahead double-buffer + next-ci ksg0 prefetch
// before the fold. B = z (-2z hi/lo f16) staged in-kernel, LDS row stride
// 1040 B (conflict-free). Aug-MFMA-first with C=0 initializes acc + ||e||^2.
// Fold packs m + ||z_row||^2 (true distance) for the z-free final.
// LDS: z 133,120 | run 8,192 | zn 512 = 141,824 B.
__global__ __launch_bounds__(512, 2)
void vq_main(const float* __restrict__ z, const _Float16* __restrict__ et,
             u64* __restrict__ pkeys) {
    extern __shared__ char smem[];
    u64* run = (u64*)(smem + 133120);            // [8][128]
    float* zn = (float*)(smem + 141312);         // [128] ||z_row||^2

    const int tid = threadIdx.x;
    const int w = tid >> 6, L = tid & 63, lo5 = L & 31, hi1 = L >> 5;
    const int rb = blockIdx.x >> 2, sp = blockIdx.x & 3;
    const int row0 = rb * 128, codeS = sp * 2048;

    // ---- stage z: f32 loads -> (-2z) hi/lo ds_write; wave-reduce ||z||^2 ----
    const float* zr = z + (size_t)row0 * DIM;
    #pragma unroll
    for (int jj = 0; jj < 16; ++jj) {
        const int idx = jj * 512 + tid;          // float4 index in [0,8192)
        const int r = idx >> 6, q = idx & 63;    // r = jj*8 + w, q = L
        float4 v = *(const float4*)(zr + (size_t)r * DIM + q * 4);
        float xs[4] = {v.x, v.y, v.z, v.w};
        float ss = xs[0]*xs[0] + xs[1]*xs[1] + xs[2]*xs[2] + xs[3]*xs[3];
        f16x4 hh, lo;
        #pragma unroll
        for (int i = 0; i < 4; ++i) {
            const float m2 = -2.0f * xs[i];      // planes carry -2z
            _Float16 h = (_Float16)m2;
            hh[i] = h;
            lo[i] = (_Float16)(m2 - (float)h);
        }
        char* base = smem + r * 1040 + q * 8;
        *(f16x4*)(base) = hh;                    // hi plane
        *(f16x4*)(base + 512) = lo;              // lo plane
        #pragma unroll
        for (int off = 32; off > 0; off >>= 1) ss += __shfl_down(ss, off, 64);
        if (L == 0) zn[r] = ss;                  // row norm (f32)
    }
    run[tid] = ~0ULL;
    run[tid + 512] = ~0ULL;

    f16x8 bz;                                    // aug B: B[k0]=B[k1]=1 (hi1=0), else 0
    #pragma unroll
    for (int i = 0; i < 8; ++i) bz[i] = (_Float16)0;
    if (hi1 == 0) { bz[0] = (_Float16)1; bz[1] = (_Float16)1; }

    f32x16 zacc;                                 // constant C=0 for aug MFMAs
    #pragma unroll
    for (int e = 0; e < 16; ++e) zacc[e] = 0.0f;

    const f16x8* eb  = (const f16x8*)et;
    const f16x8* ebL = eb + 262144;              // lo plane
    const int laneU = lo5 * 2 + hi1;             // loop-invariant A voffset (units)
    const size_t spB = (size_t)sp * 65536;
    const char* zbA = smem + (lo5 * 1040 + hi1 * 16);
    const char* zbB = zbA + 66560;               // rows 64..127 (imm stays < 64 KB)

    // prefetch aug-A for ci=0 (hi1=1 lanes get other norms: finite, x0 in MFMA)
    f16x8 paug[2];
    {
        const int c0 = codeS + w * 64;
        paug[0] = eb[(size_t)524288 + c0 + lo5];
        paug[1] = eb[(size_t)524288 + c0 + 32 + lo5];
    }
    // prefetch A ksg=0 of ci=0 (overlaps staging + barrier)
    f16x8 aC0, aC1, aC2, aC3;
    {
        const size_t cu = spB + (size_t)(w * 64) * 2 + laneU;
        aC0 = eb[cu]; aC1 = eb[cu + 64]; aC2 = ebL[cu]; aC3 = ebL[cu + 64];
    }
    __syncthreads();

    for (int ci = 0; ci < 4; ++ci) {
        const int c0 = codeS + ci * 512 + w * 64;
        const size_t cu = spB + (size_t)(ci * 512 + w * 64) * 2 + laneU;
        f32x16 acc[2][4];

        // aug-first: acc = ||e||^2 broadcast (also the zero-init)
        __builtin_amdgcn_s_setprio(1);
        #pragma unroll
        for (int mt = 0; mt < 2; ++mt)
            #pragma unroll
            for (int nt = 0; nt < 4; ++nt)
                acc[mt][nt] = __builtin_amdgcn_mfma_f32_32x32x16_f16(paug[mt], bz, zacc, 0, 0, 0);
        __builtin_amdgcn_s_setprio(0);

        if (ci < 3) {                            // prefetch aug-A for ci+1
            const int c1 = codeS + (ci + 1) * 512 + w * 64;
            paug[0] = eb[(size_t)524288 + c1 + lo5];
            paug[1] = eb[(size_t)524288 + c1 + 32 + lo5];
        }

        #pragma unroll 4
        for (int ksg = 0; ksg < 16; ++ksg) {
            // A prefetch for ksg+1 (ksg=15 -> phantom, in-bounds, unused)
            const size_t ubn = cu + (size_t)(ksg + 1) * 4096;
            f16x8 aN0 = eb[ubn], aN1 = eb[ubn + 64];
            f16x8 aN2 = ebL[ubn], aN3 = ebL[ubn + 64];

            // first nt-half
            {
                f16x8 bh0 = *(const f16x8*)(zbA + (ksg * 32));
                f16x8 bl0 = *(const f16x8*)(zbA + (ksg * 32 + 512));
                f16x8 bh1 = *(const f16x8*)(zbA + (ksg * 32 + 33280));
                f16x8 bl1 = *(const f16x8*)(zbA + (ksg * 32 + 33280 + 512));
                __builtin_amdgcn_s_setprio(1);
                acc[0][0] = __builtin_amdgcn_mfma_f32_32x32x16_f16(aC0, bh0, acc[0][0], 0, 0, 0);
                acc[0][0] = __builtin_amdgcn_mfma_f32_32x32x16_f16(aC0, bl0, acc[0][0], 0, 0, 0);
                acc[0][0] = __builtin_amdgcn_mfma_f32_32x32x16_f16(aC2, bh0, acc[0][0], 0, 0, 0);
                acc[0][1] = __builtin_amdgcn_mfma_f32_32x32x16_f16(aC0, bh1, acc[0][1], 0, 0, 0);
                acc[0][1] = __builtin_amdgcn_mfma_f32_32x32x16_f16(aC0, bl1, acc[0][1], 0, 0, 0);
                acc[0][1] = __builtin_amdgcn_mfma_f32_32x32x16_f16(aC2, bh1, acc[0][1], 0, 0, 0);
                acc[1][0] = __builtin_amdgcn_mfma_f32_32x32x16_f16(aC1, bh0, acc[1][0], 0, 0, 0);
                acc[1][0] = __builtin_amdgcn_mfma_f32_32x32x16_f16(aC1, bl0, acc[1][0], 0, 0, 0);
                acc[1][0] = __builtin_amdgcn_mfma_f32_32x32x16_f16(aC3, bh0, acc[1][0], 0, 0, 0);
                acc[1][1] = __builtin_amdgcn_mfma_f32_32x32x16_f16(aC1, bh1, acc[1][1], 0, 0, 0);
                acc[1][1] = __builtin_amdgcn_mfma_f32_32x32x16_f16(aC1, bl1, acc[1][1], 0, 0, 0);
                acc[1][1] = __builtin_amdgcn_mfma_f32_32x32x16_f16(aC3, bh1, acc[1][1], 0, 0, 0);
                __builtin_amdgcn_s_setprio(0);
            }
            // second nt-half
            {
                f16x8 bh2 = *(const f16x8*)(zbB + (ksg * 32));
                f16x8 bl2 = *(const f16x8*)(zbB + (ksg * 32 + 512));
                f16x8 bh3 = *(const f16x8*)(zbB + (ksg * 32 + 33280));
                f16x8 bl3 = *(const f16x8*)(zbB + (ksg * 32 + 33280 + 512));
                __builtin_amdgcn_s_setprio(1);
                acc[0][2] = __builtin_amdgcn_mfma_f32_32x32x16_f16(aC0, bh2, acc[0][2], 0, 0, 0);
                acc[0][2] = __builtin_amdgcn_mfma_f32_32x32x16_f16(aC0, bl2, acc[0][2], 0, 0, 0);
                acc[0][2] = __builtin_amdgcn_mfma_f32_32x32x16_f16(aC2, bh2, acc[0][2], 0, 0, 0);
                acc[0][3] = __builtin_amdgcn_mfma_f32_32x32x16_f16(aC0, bh3, acc[0][3], 0, 0, 0);
                acc[0][3] = __builtin_amdgcn_mfma_f32_32x32x16_f16(aC0, bl3, acc[0][3], 0, 0, 0);
                acc[0][3] = __builtin_amdgcn_mfma_f32_32x32x16_f16(aC2, bh3, acc[0][3], 0, 0, 0);
                acc[1][2] = __builtin_amdgcn_mfma_f32_32x32x16_f16(aC1, bh2, acc[1][2], 0, 0, 0);
                acc[1][2] = __builtin_amdgcn_mfma_f32_32x32x16_f16(aC1, bl2, acc[1][2], 0, 0, 0);
                acc[1][2] = __builtin_amdgcn_mfma_f32_32x32x16_f16(aC3, bh2, acc[1][2], 0, 0, 0);
                acc[1][3] = __builtin_amdgcn_mfma_f32_32x32x16_f16(aC1, bh3, acc[1][3], 0, 0, 0);
                acc[1][3] = __builtin_amdgcn_mfma_f32_32x32x16_f16(aC1, bl3, acc[1][3], 0, 0, 0);
                acc[1][3] = __builtin_amdgcn_mfma_f32_32x32x16_f16(aC3, bh3, acc[1][3], 0, 0, 0);
                __builtin_amdgcn_s_setprio(0);
            }
            aC0 = aN0; aC1 = aN1; aC2 = aN2; aC3 = aN3;
        }

        // prefetch A ksg=0 of next ci BEFORE the fold (hides L2 latency under fold)
        {
            const size_t cuN = spB + (size_t)((((ci + 1) & 3) * 512) + w * 64) * 2 + laneU;
            aC0 = eb[cuN]; aC1 = eb[cuN + 64]; aC2 = ebL[cuN]; aC3 = ebL[cuN + 64];
        }

        // ---- fold: min-tree + first-match index; pack TRUE distance (+||z||^2) ----
        #pragma unroll
        for (int nt = 0; nt < 4; ++nt) {
            float mm[16];
            #pragma unroll
            for (int r = 0; r < 16; ++r)
                mm[r] = fminf(acc[0][nt][r], acc[1][nt][r]);
            #pragma unroll
            for (int s2 = 8; s2 > 0; s2 >>= 1)
                #pragma unroll
                for (int r = 0; r < 8; ++r)
                    if (r < s2) mm[r] = fminf(mm[r], mm[r + s2]);
            const float m = mm[0];
            int rel = 64;                        // sentinel; rc max 59
            #pragma unroll
            for (int mt = 0; mt < 2; ++mt)
                #pragma unroll
                for (int r = 0; r < 16; ++r) {
                    const int rc = mt * 32 + (r & 3) + 8 * (r >> 2);
                    const int cand = (acc[mt][nt][r] == m) ? rc : 64;
                    rel = cand < rel ? cand : rel;   // monotone rc => lowest code wins
                }
            const float zrow = zn[nt * 32 + lo5];    // this lane's z-row norm
            u64 best = packkey(m + zrow, c0 + 4 * hi1 + rel);
            const u64 o = __shfl_xor(best, 32, 64);  // merge code-halves (same row)
            if (o < best) best = o;
            if (hi1 == 0) {
                u64* p = &run[w * 128 + nt * 32 + lo5];  // sole writer per slot
                if (best < *p) *p = best;
            }
        }
    }

    __syncthreads();
    if (tid < 128) {                             // merge 8 waves, then cross-split
        u64 k = run[tid];
        #pragma unroll
        for (int w2 = 1; w2 < 8; ++w2) { u64 o = run[w2 * 128 + tid]; if (o < k) k = o; }
        atomicMin(&pkeys[row0 + tid], k);
    }
}

// ---------------- final: idx + loss decoded from pkeys; e-gather -> z_q ----------------
// No z read: key's hi word IS the (monotone-mapped) true distance ||z-e||^2.
__global__ __launch_bounds__(256)
void vq_final(const float* __restrict__ emb, const u64* __restrict__ pkeys,
              float* __restrict__ zq_out, float* __restrict__ loss_out,
              float* __restrict__ idx_out) {
    __shared__ int bestc[64];
    const int t = threadIdx.x;
    const int row0 = blockIdx.x * 64;
    if (t < 64) {                                // wave 0
        const u64 k = pkeys[row0 + t];
        const int code = (int)(k & 0xFFFFFFFFu);
        unsigned int mu = (unsigned int)(k >> 32);
        mu = (mu & 0x80000000u) ? (mu ^ 0x80000000u) : ~mu;  // inverse monotone map
        float d = __uint_as_float(mu);
        bestc[t] = code;
        idx_out[row0 + t] = (float)code;
        #pragma unroll
        for (int off = 32; off > 0; off >>= 1) d += __shfl_down(d, off, 64);
        if (t == 0) atomicAdd(loss_out, d * (1.25f / (float)ZQ_ELEMS));
    }
    __syncthreads();
    const int wave = t >> 6, lane = t & 63;      // 4 waves x 16 rows
    #pragma unroll
    for (int rr = 0; rr < 16; ++rr) {
        const int rl = wave * 16 + rr;
        const int code = bestc[rl];
        float4 ev = *(const float4*)(emb + (size_t)code * DIM + lane * 4);
        *(float4*)(zq_out + (size_t)(row0 + rl) * DIM + lane * 4) = ev;
    }
}

extern "C" void kernel_launch(void* const* d_in, const int* in_sizes, int n_in,
                              void* d_out, int out_size, void* d_ws, size_t ws_size,
                              hipStream_t stream) {
    const float* z   = (const float*)d_in[0];
    const float* emb = (const float*)d_in[1];
    float* out  = (float*)d_out;
    float* zq   = out;
    float* loss = out + ZQ_ELEMS;
    float* idx  = out + ZQ_ELEMS + 1;

    char* ws = (char*)d_ws;
    _Float16* et = (_Float16*)(ws + WS_ET);
    u64*   pk    = (u64*)(ws + WS_PK);

    static bool attr_set = false;
    if (!attr_set) {
        hipFuncSetAttribute((const void*)vq_main,
                            hipFuncAttributeMaxDynamicSharedMemorySize, 141824);
        attr_set = true;
    }

    vq_prep<<<256, 256, 0, stream>>>(emb, et, pk, loss);
    vq_main<<<512, 512, 141824, stream>>>(z, et, pk);
    vq_final<<<N_ROWS / 64, 256, 0, stream>>>(emb, pk, zq, loss, idx);
}